// Round 1
// 966.470 us; speedup vs baseline: 1.0275x; 1.0275x over previous
//
#include <hip/hip_runtime.h>

#define N_NODES 50000
#define N_EDGES 250000
#define DIM 256          // IN = OUT = H*C
#define ED 194           // edge feature dim
#define EDP 224          // padded to multiple of 32
#define MP_NODE 50048    // 391*128
#define MP_EDGE 250112   // 1954*128

typedef __bf16 bf16x8 __attribute__((ext_vector_type(8)));
typedef float f32x4 __attribute__((ext_vector_type(4)));
typedef short s16x8 __attribute__((ext_vector_type(8)));
typedef short s16x4 __attribute__((ext_vector_type(4)));

__device__ __forceinline__ float bf2f(unsigned short b){
  union { unsigned int u; float f; } v; v.u = ((unsigned int)b)<<16; return v.f;
}
__device__ __forceinline__ short f2bf(float f){
  union { float f; unsigned int u; } v; v.f = f;
  unsigned int u = v.u;
  return (short)((u + 0x7fffu + ((u>>16)&1u))>>16);
}

// async global->LDS, 16B per lane. LDS dest = wave-uniform base + lane*16.
__device__ __forceinline__ void gload_lds16(const void* g, void* l){
  __builtin_amdgcn_global_load_lds(
      (const __attribute__((address_space(1))) unsigned int*)g,
      (__attribute__((address_space(3))) unsigned int*)l, 16, 0, 0);
}

// ---------------- input converts (fp32 -> bf16, padded) ----------------
// x rows are exactly DIM=256 floats -> flat layout identical in and out.
// Dense mapping: thread i handles float4 #i (16B load, 8B store, fully coalesced).
__global__ __launch_bounds__(256) void convert_x_kernel(
    const float* __restrict__ x, short* __restrict__ xb)
{
  int idx = blockIdx.x*256 + threadIdx.x;       // MP_NODE*64 float4s total
  s16x4 o;
  if (idx < N_NODES*64){
    float4 a = *(const float4*)(x + (size_t)idx*4);
    o[0]=f2bf(a.x); o[1]=f2bf(a.y); o[2]=f2bf(a.z); o[3]=f2bf(a.w);
  } else {
    o[0]=0; o[1]=0; o[2]=0; o[3]=0;
  }
  *(s16x4*)(xb + (size_t)idx*4) = o;
}

// Edge rows are 194 floats (776B, only 8B-aligned) -> stage 32 rows through
// LDS with dense flat float4 loads (block start = blk*24832B, 16B-aligned),
// then convert+pad with coalesced s16x8 stores. Valid-region boundary is
// float4-aligned (32*194 and tail 16*194 both %4==0), so a per-float4 guard
// suffices and pad blocks write zeros.
#define E_ROWS 32
__global__ __launch_bounds__(256) void convert_e_kernel(
    const float* __restrict__ ea, short* __restrict__ eb)
{
  __shared__ float lds[E_ROWS*ED];              // 6208 floats = 24832 B
  int row0 = blockIdx.x * E_ROWS;
  int tid = threadIdx.x;
  int base = row0 * ED;                         // float index of block start
  int valid = N_EDGES*ED - base;                // may be <=0 for pad blocks

  for (int i = tid; i < E_ROWS*ED/4; i += 256){
    float4 v;
    if (i*4 < valid) v = *(const float4*)(ea + base + i*4);
    else             v = make_float4(0.f,0.f,0.f,0.f);
    *(float4*)(lds + i*4) = v;
  }
  __syncthreads();

  for (int u = tid; u < E_ROWS*28; u += 256){
    int row = u / 28;
    int c8  = u - row*28;
    int col = c8*8;
    s16x8 o;
    if (col + 8 <= ED){
      #pragma unroll
      for (int j2=0;j2<4;j2++){
        float2 f = *(const float2*)(lds + row*ED + col + j2*2);
        o[j2*2]   = f2bf(f.x);
        o[j2*2+1] = f2bf(f.y);
      }
    } else {
      #pragma unroll
      for (int j=0;j<8;j++){
        int c = col + j;
        o[j] = (c < ED) ? f2bf(lds[row*ED + c]) : (short)0;
      }
    }
    *(s16x8*)(eb + (size_t)(row0+row)*EDP + col) = o;
  }
}

// ---------------- weight transforms (coalesced reads) ----------------
// WtN layout: [w][o][i] == B^T[n][k], n = w*256+o  (bf16)
__global__ __launch_bounds__(256) void transpose_node_w(
    const float* __restrict__ Wq, const float* __restrict__ Wk,
    const float* __restrict__ Wv, const float* __restrict__ Ws,
    short* __restrict__ WtN)
{
  int idx = blockIdx.x*256 + threadIdx.x;      // 4*65536 total
  int w = idx>>16, rem = idx&65535;
  int i = rem>>8, o = rem&255;                 // o fast -> coalesced read
  const float* W = (w==0)?Wq:((w==1)?Wk:((w==2)?Wv:Ws));
  WtN[(w<<16) + o*256 + i] = f2bf(W[i*256+o]);
}
__global__ __launch_bounds__(256) void bias_cat_kernel(
    const float* __restrict__ b0, const float* __restrict__ b1,
    const float* __restrict__ b2, const float* __restrict__ b3,
    float* __restrict__ biasN)
{
  int t = blockIdx.x*256 + threadIdx.x;        // 1024
  const float* b = (t<256)?b0:((t<512)?b1:((t<768)?b2:b3));
  biasN[t] = b[t&255];
}
// WtE layout: [o][k] padded to EDP with zeros (bf16)
__global__ __launch_bounds__(256) void transpose_edge_w(
    const float* __restrict__ We, short* __restrict__ WtE)
{
  int idx = blockIdx.x*256 + threadIdx.x;      // 224*256 total
  int k = idx>>8, o = idx&255;                 // o fast -> coalesced read
  WtE[o*EDP + k] = (k<ED) ? f2bf(We[k*256+o]) : (short)0;
}

// ---------------- CSR build ----------------
__global__ __launch_bounds__(256) void zero_ints(int* __restrict__ p, int n){
  int i = blockIdx.x*256 + threadIdx.x;
  if (i<n) p[i] = 0;
}
__global__ __launch_bounds__(256) void count_deg(const int* __restrict__ dst, int* __restrict__ deg){
  int e = blockIdx.x*256 + threadIdx.x;
  if (e < N_EDGES) atomicAdd(&deg[dst[e]], 1);
}
#define SCAN_NBLK 196
__global__ __launch_bounds__(256) void scan_p1(const int* __restrict__ deg, int* __restrict__ part){
  int t = threadIdx.x;
  int i = blockIdx.x*256 + t;
  int v = (i<N_NODES)? deg[i] : 0;
  #pragma unroll
  for (int off=32; off; off>>=1) v += __shfl_xor(v, off, 64);
  __shared__ int s[4];
  if ((t&63)==0) s[t>>6] = v;
  __syncthreads();
  if (t==0) part[blockIdx.x] = s[0]+s[1]+s[2]+s[3];
}
__global__ __launch_bounds__(256) void scan_p2(int* __restrict__ part){
  __shared__ int s[256];
  int t = threadIdx.x;
  int v = (t<SCAN_NBLK)? part[t] : 0;
  s[t] = v; __syncthreads();
  for (int off=1; off<256; off<<=1){
    int x = (t>=off)? s[t-off] : 0;
    __syncthreads();
    s[t] += x;
    __syncthreads();
  }
  part[t] = (t==0)? 0 : s[t-1];
}
// also zeroes cursor
__global__ __launch_bounds__(256) void scan_p3(const int* __restrict__ deg,
    const int* __restrict__ part, int* __restrict__ rowptr, int* __restrict__ cursor){
  __shared__ int s[256];
  int t = threadIdx.x;
  int i = blockIdx.x*256 + t;
  int v = (i<N_NODES)? deg[i] : 0;
  s[t] = v; __syncthreads();
  for (int off=1; off<256; off<<=1){
    int x = (t>=off)? s[t-off] : 0;
    __syncthreads();
    s[t] += x;
    __syncthreads();
  }
  if (i < N_NODES){ rowptr[i+1] = part[blockIdx.x] + s[t]; cursor[i] = 0; }
  if (i == 0) rowptr[0] = 0;
}
// csr entries premultiplied to byte offsets: x = src*2048 (QKVS row), y = e*512 (Eemb row)
__global__ __launch_bounds__(256) void scatter_edges(
    const int* __restrict__ src, const int* __restrict__ dst,
    const int* __restrict__ rowptr, int* __restrict__ cursor, int2* __restrict__ csr)
{
  int e = blockIdx.x*256 + threadIdx.x;
  if (e < N_EDGES){
    int d = dst[e];
    int pos = atomicAdd(&cursor[d], 1);
    csr[rowptr[d] + pos] = make_int2(src[e]<<11, e<<9);
  }
}

// ---------------- tiled GEMM: out = A(bf16,[Mpad][K]) @ Bt^T (Bt=[N][K] bf16) ----------------
template<int K, int NLD, bool HAS_BIAS>
__global__ __launch_bounds__(256) void gemm_bt(
    const short* __restrict__ A, const short* __restrict__ Bt,
    const float* __restrict__ bias, short* __restrict__ out, int M)
{
  __shared__ short As[128*32];
  __shared__ short Bs[128*32];
  int tid = threadIdx.x;
  int lane = tid & 63, wave = tid >> 6;
  int m0 = blockIdx.x*128, n0 = blockIdx.y*128;

  int srow = tid>>2, scol = (tid&3)*8;
  const short* gA = A + (size_t)(m0+srow)*K + scol;
  const short* gB = Bt + (size_t)(n0+srow)*K + scol;
  short* ldsA1 = As + wave*512;
  short* ldsA2 = As + 2048 + wave*512;
  short* ldsB1 = Bs + wave*512;
  short* ldsB2 = Bs + 2048 + wave*512;

  int wr = wave>>1, wc = wave&1;
  int fr = lane & 15;
  int kq = lane >> 4;
  f32x4 acc[4][4];
  #pragma unroll
  for (int a=0;a<4;a++)
    #pragma unroll
    for (int b=0;b<4;b++) acc[a][b] = (f32x4){0.f,0.f,0.f,0.f};

  for (int k0=0; k0<K; k0+=32){
    __syncthreads();
    gload_lds16(gA + k0,                ldsA1);
    gload_lds16(gA + (size_t)64*K + k0, ldsA2);
    gload_lds16(gB + k0,                ldsB1);
    gload_lds16(gB + (size_t)64*K + k0, ldsB2);
    __syncthreads();

    bf16x8 af[4], bf[4];
    const short* ar = As + (wr*64 + fr)*32 + kq*8;
    const short* br = Bs + (wc*64 + fr)*32 + kq*8;
    #pragma unroll
    for (int fm=0;fm<4;fm++) af[fm] = *(const bf16x8*)(ar + fm*512);
    #pragma unroll
    for (int fn=0;fn<4;fn++) bf[fn] = *(const bf16x8*)(br + fn*512);
    #pragma unroll
    for (int fm=0;fm<4;fm++)
      #pragma unroll
      for (int fn=0;fn<4;fn++)
        acc[fm][fn] = __builtin_amdgcn_mfma_f32_16x16x32_bf16(af[fm], bf[fn], acc[fm][fn], 0, 0, 0);
  }

  int cr = (lane>>4)*4;
  int cc = lane & 15;
  #pragma unroll
  for (int fm=0;fm<4;fm++){
    #pragma unroll
    for (int fn=0;fn<4;fn++){
      int col = n0 + wc*64 + fn*16 + cc;
      float bv = HAS_BIAS ? bias[col] : 0.f;
      #pragma unroll
      for (int i=0;i<4;i++){
        int row = m0 + wr*64 + fm*16 + cr + i;
        if (row < M) out[(size_t)row*NLD + col] = f2bf(acc[fm][fn][i] + bv);
      }
    }
  }
}

// ---------------- fused edge phase ----------------
// block = node, 4 waves. Wave w handles edges beg+w, beg+w+4, ... ONE edge per
// iteration across ALL 4 heads: lane covers channels lane*4..+3 (head=lane>>4).
// Per-head logit via 16-lane xor reduce. No max subtraction (logits are small;
// exact same math in fp32). Cross-wave merge of (l, acc) via LDS: pure adds.
__global__ __launch_bounds__(256) void edge_phase_kernel(
    const short* __restrict__ QKVS, const short* __restrict__ Eemb,
    const int* __restrict__ rowptr, const int2* __restrict__ csr,
    short* __restrict__ out_bf, float* __restrict__ out_f, int relu)
{
  __shared__ float accs[4][256];
  __shared__ float lsum[4][4];
  int node = blockIdx.x;
  int tid = threadIdx.x, wave = tid>>6, lane = tid&63;
  if (node >= N_NODES){
    if (out_bf) out_bf[(size_t)node*256 + tid] = 0;
    return;
  }
  int c4 = lane*4;
  const unsigned short* base = (const unsigned short*)QKVS + (size_t)node*1024;
  ushort4 qu = *(const ushort4*)(base + c4);
  float q0 = bf2f(qu.x)*0.125f, q1 = bf2f(qu.y)*0.125f;
  float q2 = bf2f(qu.z)*0.125f, q3 = bf2f(qu.w)*0.125f;

  int beg = rowptr[node], end = rowptr[node+1];
  float l = 0.f, a0=0.f, a1=0.f, a2=0.f, a3=0.f;
  int koff = 512 + lane*8;      // K block byte offset within QKVS row + lane quad
  int eoff = lane*8;

  for (int idx = beg + wave; idx < end; idx += 4){
    int2 se = csr[idx];         // .x = src*2048 bytes, .y = e*512 bytes
    const char* Kp = (const char*)QKVS + (unsigned)(se.x + koff);
    const char* Ep = (const char*)Eemb + (unsigned)(se.y + eoff);
    ushort4 ku = *(const ushort4*)Kp;
    ushort4 vu = *(const ushort4*)(Kp + 512);   // V block
    ushort4 eu = *(const ushort4*)Ep;
    float e0 = bf2f(eu.x), e1 = bf2f(eu.y), e2 = bf2f(eu.z), e3 = bf2f(eu.w);
    float k0 = bf2f(ku.x)+e0, k1 = bf2f(ku.y)+e1, k2 = bf2f(ku.z)+e2, k3 = bf2f(ku.w)+e3;
    float v0 = bf2f(vu.x)+e0, v1 = bf2f(vu.y)+e1, v2 = bf2f(vu.z)+e2, v3 = bf2f(vu.w)+e3;
    float t = q0*k0 + q1*k1 + q2*k2 + q3*k3;
    t += __shfl_xor(t, 1, 64);
    t += __shfl_xor(t, 2, 64);
    t += __shfl_xor(t, 4, 64);
    t += __shfl_xor(t, 8, 64);
    float p = __expf(t);
    l  += p;
    a0 += p*v0; a1 += p*v1; a2 += p*v2; a3 += p*v3;
  }

  *(float4*)&accs[wave][c4] = make_float4(a0, a1, a2, a3);
  if ((lane&15)==0) lsum[wave][lane>>4] = l;
  __syncthreads();

  int ch = tid, head = tid>>6;
  float A = accs[0][ch] + accs[1][ch] + accs[2][ch] + accs[3][ch];
  float L = lsum[0][head] + lsum[1][head] + lsum[2][head] + lsum[3][head];
  float inv = (L > 0.f) ? 1.0f/L : 0.f;
  float r = A*inv + bf2f(base[768 + ch]);   // skip = x@Ws + bs
  if (relu) r = fmaxf(r, 0.f);
  if (out_bf) out_bf[(size_t)node*256 + ch] = f2bf(r);
  else        out_f [(size_t)node*256 + ch] = r;
}

// ---------------- launch ----------------
extern "C" void kernel_launch(void* const* d_in, const int* in_sizes, int n_in,
                              void* d_out, int out_size, void* d_ws, size_t ws_size,
                              hipStream_t stream)
{
  const float* x     = (const float*)d_in[0];
  const int*   eidx  = (const int*)d_in[1];
  const float* eattr = (const float*)d_in[2];
  const float* Wq1=(const float*)d_in[3],  *bq1=(const float*)d_in[4];
  const float* Wk1=(const float*)d_in[5],  *bk1=(const float*)d_in[6];
  const float* Wv1=(const float*)d_in[7],  *bv1=(const float*)d_in[8];
  const float* We1=(const float*)d_in[9];
  const float* Ws1=(const float*)d_in[10], *bs1=(const float*)d_in[11];
  const float* Wq2=(const float*)d_in[12], *bq2=(const float*)d_in[13];
  const float* Wk2=(const float*)d_in[14], *bk2=(const float*)d_in[15];
  const float* Wv2=(const float*)d_in[16], *bv2=(const float*)d_in[17];
  const float* We2=(const float*)d_in[18];
  const float* Ws2=(const float*)d_in[19], *bs2=(const float*)d_in[20];

  char* ws = (char*)d_ws;
  size_t off = 0;
  auto alloc = [&](size_t bytes)->char*{
    char* p = ws + off; off = (off + bytes + 255) & ~(size_t)255; return p;
  };
  short* QKVS  = (short*)alloc((size_t)N_NODES*1024*2);
  short* Eemb  = (short*)alloc((size_t)N_EDGES*256*2);
  short* x_bf  = (short*)alloc((size_t)MP_NODE*DIM*2);
  short* h_bf  = (short*)alloc((size_t)MP_NODE*DIM*2);
  short* e_bf  = (short*)alloc((size_t)MP_EDGE*EDP*2);
  short* WtN   = (short*)alloc((size_t)4*65536*2);
  short* WtE   = (short*)alloc((size_t)256*EDP*2);
  float* biasN = (float*)alloc((size_t)1024*4);
  int*   deg   = (int*)alloc((size_t)N_NODES*4);
  int*   rowptr= (int*)alloc((size_t)(N_NODES+1)*4);
  int*   cursor= (int*)alloc((size_t)N_NODES*4);
  int*   part  = (int*)alloc((size_t)256*4);
  int2*  csr   = (int2*)alloc((size_t)N_EDGES*8);

  const int* srcp = eidx;
  const int* dstp = eidx + N_EDGES;

  const int EB = (N_EDGES + 255)/256;   // 977
  const int NB = (N_NODES + 255)/256;   // 196

  convert_x_kernel<<<MP_NODE*64/256,256,0,stream>>>(x, x_bf);
  convert_e_kernel<<<MP_EDGE/E_ROWS,256,0,stream>>>(eattr, e_bf);

  zero_ints<<<NB,256,0,stream>>>(deg, N_NODES);
  count_deg<<<EB,256,0,stream>>>(dstp, deg);
  scan_p1<<<SCAN_NBLK,256,0,stream>>>(deg, part);
  scan_p2<<<1,256,0,stream>>>(part);
  scan_p3<<<SCAN_NBLK,256,0,stream>>>(deg, part, rowptr, cursor);
  scatter_edges<<<EB,256,0,stream>>>(srcp, dstp, rowptr, cursor, csr);

  // ---- conv1 ----
  transpose_node_w<<<1024,256,0,stream>>>(Wq1,Wk1,Wv1,Ws1,WtN);
  bias_cat_kernel<<<4,256,0,stream>>>(bq1,bk1,bv1,bs1,biasN);
  transpose_edge_w<<<224,256,0,stream>>>(We1,WtE);
  gemm_bt<DIM,1024,true><<<dim3(MP_NODE/128,8),256,0,stream>>>(x_bf, WtN, biasN, QKVS, N_NODES);
  gemm_bt<EDP,256,false><<<dim3(MP_EDGE/128,2),256,0,stream>>>(e_bf, WtE, nullptr, Eemb, N_EDGES);
  edge_phase_kernel<<<MP_NODE,256,0,stream>>>(QKVS,Eemb,rowptr,csr,h_bf,nullptr,1);

  // ---- conv2 ----
  transpose_node_w<<<1024,256,0,stream>>>(Wq2,Wk2,Wv2,Ws2,WtN);
  bias_cat_kernel<<<4,256,0,stream>>>(bq2,bk2,bv2,bs2,biasN);
  transpose_edge_w<<<224,256,0,stream>>>(We2,WtE);
  gemm_bt<DIM,1024,true><<<dim3(MP_NODE/128,8),256,0,stream>>>(h_bf, WtN, biasN, QKVS, N_NODES);
  gemm_bt<EDP,256,false><<<dim3(MP_EDGE/128,2),256,0,stream>>>(e_bf, WtE, nullptr, Eemb, N_EDGES);
  edge_phase_kernel<<<N_NODES,256,0,stream>>>(QKVS,Eemb,rowptr,csr,nullptr,(float*)d_out,0);
}

// Round 2
// 877.609 us; speedup vs baseline: 1.1315x; 1.1013x over previous
//
#include <hip/hip_runtime.h>

#define N_NODES 50000
#define N_EDGES 250000
#define DIM 256          // IN = OUT = H*C
#define ED 194           // edge feature dim
#define EDP 224          // padded to multiple of 32
#define MP_NODE 50048    // 391*128
#define MP_EDGE 250112   // 1954*128

typedef __bf16 bf16x8 __attribute__((ext_vector_type(8)));
typedef float f32x4 __attribute__((ext_vector_type(4)));
typedef short s16x8 __attribute__((ext_vector_type(8)));
typedef short s16x4 __attribute__((ext_vector_type(4)));
typedef unsigned short u16x8 __attribute__((ext_vector_type(8)));

__device__ __forceinline__ float bf2f(unsigned short b){
  union { unsigned int u; float f; } v; v.u = ((unsigned int)b)<<16; return v.f;
}
__device__ __forceinline__ short f2bf(float f){
  union { float f; unsigned int u; } v; v.f = f;
  unsigned int u = v.u;
  return (short)((u + 0x7fffu + ((u>>16)&1u))>>16);
}

// async global->LDS, 16B per lane. LDS dest = wave-uniform base + lane*16.
__device__ __forceinline__ void gload_lds16(const void* g, void* l){
  __builtin_amdgcn_global_load_lds(
      (const __attribute__((address_space(1))) unsigned int*)g,
      (__attribute__((address_space(3))) unsigned int*)l, 16, 0, 0);
}

// ---------------- input converts (fp32 -> bf16, padded) ----------------
// x rows are exactly DIM=256 floats -> flat layout identical in and out.
// Dense mapping: thread i handles float4 #i (16B load, 8B store, fully coalesced).
__global__ __launch_bounds__(256) void convert_x_kernel(
    const float* __restrict__ x, short* __restrict__ xb)
{
  int idx = blockIdx.x*256 + threadIdx.x;       // MP_NODE*64 float4s total
  s16x4 o;
  if (idx < N_NODES*64){
    float4 a = *(const float4*)(x + (size_t)idx*4);
    o[0]=f2bf(a.x); o[1]=f2bf(a.y); o[2]=f2bf(a.z); o[3]=f2bf(a.w);
  } else {
    o[0]=0; o[1]=0; o[2]=0; o[3]=0;
  }
  *(s16x4*)(xb + (size_t)idx*4) = o;
}

// Edge rows are 194 floats (776B, only 8B-aligned) -> stage 32 rows through
// LDS with dense flat float4 loads (block start = blk*24832B, 16B-aligned),
// then convert+pad with coalesced s16x8 stores. Valid-region boundary is
// float4-aligned (32*194 and tail 16*194 both %4==0), so a per-float4 guard
// suffices and pad blocks write zeros.
#define E_ROWS 32
__global__ __launch_bounds__(256) void convert_e_kernel(
    const float* __restrict__ ea, short* __restrict__ eb)
{
  __shared__ float lds[E_ROWS*ED];              // 6208 floats = 24832 B
  int row0 = blockIdx.x * E_ROWS;
  int tid = threadIdx.x;
  int base = row0 * ED;                         // float index of block start
  int valid = N_EDGES*ED - base;                // may be <=0 for pad blocks

  for (int i = tid; i < E_ROWS*ED/4; i += 256){
    float4 v;
    if (i*4 < valid) v = *(const float4*)(ea + base + i*4);
    else             v = make_float4(0.f,0.f,0.f,0.f);
    *(float4*)(lds + i*4) = v;
  }
  __syncthreads();

  for (int u = tid; u < E_ROWS*28; u += 256){
    int row = u / 28;
    int c8  = u - row*28;
    int col = c8*8;
    s16x8 o;
    if (col + 8 <= ED){
      #pragma unroll
      for (int j2=0;j2<4;j2++){
        float2 f = *(const float2*)(lds + row*ED + col + j2*2);
        o[j2*2]   = f2bf(f.x);
        o[j2*2+1] = f2bf(f.y);
      }
    } else {
      #pragma unroll
      for (int j=0;j<8;j++){
        int c = col + j;
        o[j] = (c < ED) ? f2bf(lds[row*ED + c]) : (short)0;
      }
    }
    *(s16x8*)(eb + (size_t)(row0+row)*EDP + col) = o;
  }
}

// ---------------- weight transforms (coalesced reads) ----------------
// WtN layout: [w][o][i] == B^T[n][k], n = w*256+o  (bf16)
__global__ __launch_bounds__(256) void transpose_node_w(
    const float* __restrict__ Wq, const float* __restrict__ Wk,
    const float* __restrict__ Wv, const float* __restrict__ Ws,
    short* __restrict__ WtN)
{
  int idx = blockIdx.x*256 + threadIdx.x;      // 4*65536 total
  int w = idx>>16, rem = idx&65535;
  int i = rem>>8, o = rem&255;                 // o fast -> coalesced read
  const float* W = (w==0)?Wq:((w==1)?Wk:((w==2)?Wv:Ws));
  WtN[(w<<16) + o*256 + i] = f2bf(W[i*256+o]);
}
__global__ __launch_bounds__(256) void bias_cat_kernel(
    const float* __restrict__ b0, const float* __restrict__ b1,
    const float* __restrict__ b2, const float* __restrict__ b3,
    float* __restrict__ biasN)
{
  int t = blockIdx.x*256 + threadIdx.x;        // 1024
  const float* b = (t<256)?b0:((t<512)?b1:((t<768)?b2:b3));
  biasN[t] = b[t&255];
}
// WtE layout: [o][k] padded to EDP with zeros (bf16)
__global__ __launch_bounds__(256) void transpose_edge_w(
    const float* __restrict__ We, short* __restrict__ WtE)
{
  int idx = blockIdx.x*256 + threadIdx.x;      // 224*256 total
  int k = idx>>8, o = idx&255;                 // o fast -> coalesced read
  WtE[o*EDP + k] = (k<ED) ? f2bf(We[k*256+o]) : (short)0;
}

// ---------------- CSR build ----------------
__global__ __launch_bounds__(256) void zero_ints(int* __restrict__ p, int n){
  int i = blockIdx.x*256 + threadIdx.x;
  if (i<n) p[i] = 0;
}
__global__ __launch_bounds__(256) void count_deg(const int* __restrict__ dst, int* __restrict__ deg){
  int e = blockIdx.x*256 + threadIdx.x;
  if (e < N_EDGES) atomicAdd(&deg[dst[e]], 1);
}
#define SCAN_NBLK 196
__global__ __launch_bounds__(256) void scan_p1(const int* __restrict__ deg, int* __restrict__ part){
  int t = threadIdx.x;
  int i = blockIdx.x*256 + t;
  int v = (i<N_NODES)? deg[i] : 0;
  #pragma unroll
  for (int off=32; off; off>>=1) v += __shfl_xor(v, off, 64);
  __shared__ int s[4];
  if ((t&63)==0) s[t>>6] = v;
  __syncthreads();
  if (t==0) part[blockIdx.x] = s[0]+s[1]+s[2]+s[3];
}
__global__ __launch_bounds__(256) void scan_p2(int* __restrict__ part){
  __shared__ int s[256];
  int t = threadIdx.x;
  int v = (t<SCAN_NBLK)? part[t] : 0;
  s[t] = v; __syncthreads();
  for (int off=1; off<256; off<<=1){
    int x = (t>=off)? s[t-off] : 0;
    __syncthreads();
    s[t] += x;
    __syncthreads();
  }
  part[t] = (t==0)? 0 : s[t-1];
}
// also zeroes cursor
__global__ __launch_bounds__(256) void scan_p3(const int* __restrict__ deg,
    const int* __restrict__ part, int* __restrict__ rowptr, int* __restrict__ cursor){
  __shared__ int s[256];
  int t = threadIdx.x;
  int i = blockIdx.x*256 + t;
  int v = (i<N_NODES)? deg[i] : 0;
  s[t] = v; __syncthreads();
  for (int off=1; off<256; off<<=1){
    int x = (t>=off)? s[t-off] : 0;
    __syncthreads();
    s[t] += x;
    __syncthreads();
  }
  if (i < N_NODES){ rowptr[i+1] = part[blockIdx.x] + s[t]; cursor[i] = 0; }
  if (i == 0) rowptr[0] = 0;
}
// csr entries premultiplied to byte offsets: x = src*2048 (QKVS row), y = e*512 (Eemb row)
__global__ __launch_bounds__(256) void scatter_edges(
    const int* __restrict__ src, const int* __restrict__ dst,
    const int* __restrict__ rowptr, int* __restrict__ cursor, int2* __restrict__ csr)
{
  int e = blockIdx.x*256 + threadIdx.x;
  if (e < N_EDGES){
    int d = dst[e];
    int pos = atomicAdd(&cursor[d], 1);
    csr[rowptr[d] + pos] = make_int2(src[e]<<11, e<<9);
  }
}

// ---------------- tiled GEMM: out = A(bf16,[Mpad][K]) @ Bt^T (Bt=[N][K] bf16) ----------------
template<int K, int NLD, bool HAS_BIAS>
__global__ __launch_bounds__(256) void gemm_bt(
    const short* __restrict__ A, const short* __restrict__ Bt,
    const float* __restrict__ bias, short* __restrict__ out, int M)
{
  __shared__ short As[128*32];
  __shared__ short Bs[128*32];
  int tid = threadIdx.x;
  int lane = tid & 63, wave = tid >> 6;
  int m0 = blockIdx.x*128, n0 = blockIdx.y*128;

  int srow = tid>>2, scol = (tid&3)*8;
  const short* gA = A + (size_t)(m0+srow)*K + scol;
  const short* gB = Bt + (size_t)(n0+srow)*K + scol;
  short* ldsA1 = As + wave*512;
  short* ldsA2 = As + 2048 + wave*512;
  short* ldsB1 = Bs + wave*512;
  short* ldsB2 = Bs + 2048 + wave*512;

  int wr = wave>>1, wc = wave&1;
  int fr = lane & 15;
  int kq = lane >> 4;
  f32x4 acc[4][4];
  #pragma unroll
  for (int a=0;a<4;a++)
    #pragma unroll
    for (int b=0;b<4;b++) acc[a][b] = (f32x4){0.f,0.f,0.f,0.f};

  for (int k0=0; k0<K; k0+=32){
    __syncthreads();
    gload_lds16(gA + k0,                ldsA1);
    gload_lds16(gA + (size_t)64*K + k0, ldsA2);
    gload_lds16(gB + k0,                ldsB1);
    gload_lds16(gB + (size_t)64*K + k0, ldsB2);
    __syncthreads();

    bf16x8 af[4], bf[4];
    const short* ar = As + (wr*64 + fr)*32 + kq*8;
    const short* br = Bs + (wc*64 + fr)*32 + kq*8;
    #pragma unroll
    for (int fm=0;fm<4;fm++) af[fm] = *(const bf16x8*)(ar + fm*512);
    #pragma unroll
    for (int fn=0;fn<4;fn++) bf[fn] = *(const bf16x8*)(br + fn*512);
    #pragma unroll
    for (int fm=0;fm<4;fm++)
      #pragma unroll
      for (int fn=0;fn<4;fn++)
        acc[fm][fn] = __builtin_amdgcn_mfma_f32_16x16x32_bf16(af[fm], bf[fn], acc[fm][fn], 0, 0, 0);
  }

  int cr = (lane>>4)*4;
  int cc = lane & 15;
  #pragma unroll
  for (int fm=0;fm<4;fm++){
    #pragma unroll
    for (int fn=0;fn<4;fn++){
      int col = n0 + wc*64 + fn*16 + cc;
      float bv = HAS_BIAS ? bias[col] : 0.f;
      #pragma unroll
      for (int i=0;i<4;i++){
        int row = m0 + wr*64 + fm*16 + cr + i;
        if (row < M) out[(size_t)row*NLD + col] = f2bf(acc[fm][fn][i] + bv);
      }
    }
  }
}

// ---------------- fused edge phase ----------------
// ONE WAVE PER NODE (4 nodes per block, no __syncthreads, no LDS merge).
// Within a wave: 32 lanes per edge, 8 channels per lane (16B loads), TWO edges
// in flight per iteration (half = lane>>5 selects edge). Head = 64ch = 8 lanes;
// per-head logit via 3 xor-shfls. Tail edge handled by clamped csr index and
// p=0. Cross-half merge at the end via shfl_xor(·,32) — registers only.
__global__ __launch_bounds__(256) void edge_phase_kernel(
    const short* __restrict__ QKVS, const short* __restrict__ Eemb,
    const int* __restrict__ rowptr, const int2* __restrict__ csr,
    short* __restrict__ out_bf, float* __restrict__ out_f, int relu)
{
  int tid = threadIdx.x, wave = tid>>6, lane = tid&63;
  int node = blockIdx.x*4 + wave;
  if (node >= N_NODES){
    if (node < MP_NODE && out_bf){
      s16x4 z; z[0]=0; z[1]=0; z[2]=0; z[3]=0;
      *(s16x4*)(out_bf + (size_t)node*256 + lane*4) = z;
    }
    return;
  }
  int half = lane>>5;          // which edge of the pair
  int hl   = lane&31;          // channel-group 0..31 (8 ch each)
  int c8   = hl*8;
  const unsigned short* base = (const unsigned short*)QKVS + (size_t)node*1024;

  u16x8 qu = *(const u16x8*)(base + c8);
  float q[8];
  #pragma unroll
  for (int j=0;j<8;j++) q[j] = bf2f(qu[j])*0.125f;

  int beg = rowptr[node], end = rowptr[node+1];
  float l = 0.f;
  float a[8];
  #pragma unroll
  for (int j=0;j<8;j++) a[j] = 0.f;
  int kb = 512 + hl*16;        // K byte offset within QKVS row for this lane
  int ebo = hl*16;             // Eemb byte offset

  for (int idx = beg; idx < end; idx += 2){
    int j = idx + half;
    int jc = (j < end) ? j : (end-1);
    int2 se = csr[jc];         // .x = src*2048 bytes, .y = e*512 bytes
    const char* Kp = (const char*)QKVS + (unsigned)(se.x + kb);
    const char* Ep = (const char*)Eemb + (unsigned)(se.y + ebo);
    u16x8 ku = *(const u16x8*)Kp;
    u16x8 vu = *(const u16x8*)(Kp + 512);   // V block
    u16x8 eu = *(const u16x8*)Ep;
    float vv[8];
    float t = 0.f;
    #pragma unroll
    for (int c=0;c<8;c++){
      float ef = bf2f(eu[c]);
      float kf = bf2f(ku[c]) + ef;
      vv[c]    = bf2f(vu[c]) + ef;
      t += q[c]*kf;
    }
    t += __shfl_xor(t, 1, 64);
    t += __shfl_xor(t, 2, 64);
    t += __shfl_xor(t, 4, 64);
    float p = (j < end) ? __expf(t) : 0.f;
    l += p;
    #pragma unroll
    for (int c=0;c<8;c++) a[c] += p*vv[c];
  }

  // merge the two halves (each summed a disjoint subset of edges)
  l += __shfl_xor(l, 32, 64);
  #pragma unroll
  for (int c=0;c<8;c++) a[c] += __shfl_xor(a[c], 32, 64);

  float inv = (l > 0.f) ? 1.0f/l : 0.f;
  u16x8 su = *(const u16x8*)(base + 768 + c8);   // skip = x@Ws + bs
  float r[8];
  #pragma unroll
  for (int c=0;c<8;c++){
    float v = a[c]*inv + bf2f(su[c]);
    r[c] = relu ? fmaxf(v, 0.f) : v;
  }

  if (out_bf){
    if (!half){
      s16x8 o;
      #pragma unroll
      for (int c=0;c<8;c++) o[c] = f2bf(r[c]);
      *(s16x8*)(out_bf + (size_t)node*256 + c8) = o;
    }
  } else {
    float4 st = half ? make_float4(r[4],r[5],r[6],r[7])
                     : make_float4(r[0],r[1],r[2],r[3]);
    *(float4*)(out_f + (size_t)node*256 + c8 + half*4) = st;
  }
}

// ---------------- launch ----------------
extern "C" void kernel_launch(void* const* d_in, const int* in_sizes, int n_in,
                              void* d_out, int out_size, void* d_ws, size_t ws_size,
                              hipStream_t stream)
{
  const float* x     = (const float*)d_in[0];
  const int*   eidx  = (const int*)d_in[1];
  const float* eattr = (const float*)d_in[2];
  const float* Wq1=(const float*)d_in[3],  *bq1=(const float*)d_in[4];
  const float* Wk1=(const float*)d_in[5],  *bk1=(const float*)d_in[6];
  const float* Wv1=(const float*)d_in[7],  *bv1=(const float*)d_in[8];
  const float* We1=(const float*)d_in[9];
  const float* Ws1=(const float*)d_in[10], *bs1=(const float*)d_in[11];
  const float* Wq2=(const float*)d_in[12], *bq2=(const float*)d_in[13];
  const float* Wk2=(const float*)d_in[14], *bk2=(const float*)d_in[15];
  const float* Wv2=(const float*)d_in[16], *bv2=(const float*)d_in[17];
  const float* We2=(const float*)d_in[18];
  const float* Ws2=(const float*)d_in[19], *bs2=(const float*)d_in[20];

  char* ws = (char*)d_ws;
  size_t off = 0;
  auto alloc = [&](size_t bytes)->char*{
    char* p = ws + off; off = (off + bytes + 255) & ~(size_t)255; return p;
  };
  short* QKVS  = (short*)alloc((size_t)N_NODES*1024*2);
  short* Eemb  = (short*)alloc((size_t)N_EDGES*256*2);
  short* x_bf  = (short*)alloc((size_t)MP_NODE*DIM*2);
  short* h_bf  = (short*)alloc((size_t)MP_NODE*DIM*2);
  short* e_bf  = (short*)alloc((size_t)MP_EDGE*EDP*2);
  short* WtN   = (short*)alloc((size_t)4*65536*2);
  short* WtE   = (short*)alloc((size_t)256*EDP*2);
  float* biasN = (float*)alloc((size_t)1024*4);
  int*   deg   = (int*)alloc((size_t)N_NODES*4);
  int*   rowptr= (int*)alloc((size_t)(N_NODES+1)*4);
  int*   cursor= (int*)alloc((size_t)N_NODES*4);
  int*   part  = (int*)alloc((size_t)256*4);
  int2*  csr   = (int2*)alloc((size_t)N_EDGES*8);

  const int* srcp = eidx;
  const int* dstp = eidx + N_EDGES;

  const int EB = (N_EDGES + 255)/256;   // 977
  const int NB = (N_NODES + 255)/256;   // 196

  convert_x_kernel<<<MP_NODE*64/256,256,0,stream>>>(x, x_bf);
  convert_e_kernel<<<MP_EDGE/E_ROWS,256,0,stream>>>(eattr, e_bf);

  zero_ints<<<NB,256,0,stream>>>(deg, N_NODES);
  count_deg<<<EB,256,0,stream>>>(dstp, deg);
  scan_p1<<<SCAN_NBLK,256,0,stream>>>(deg, part);
  scan_p2<<<1,256,0,stream>>>(part);
  scan_p3<<<SCAN_NBLK,256,0,stream>>>(deg, part, rowptr, cursor);
  scatter_edges<<<EB,256,0,stream>>>(srcp, dstp, rowptr, cursor, csr);

  // ---- conv1 ----
  transpose_node_w<<<1024,256,0,stream>>>(Wq1,Wk1,Wv1,Ws1,WtN);
  bias_cat_kernel<<<4,256,0,stream>>>(bq1,bk1,bv1,bs1,biasN);
  transpose_edge_w<<<224,256,0,stream>>>(We1,WtE);
  gemm_bt<DIM,1024,true><<<dim3(MP_NODE/128,8),256,0,stream>>>(x_bf, WtN, biasN, QKVS, N_NODES);
  gemm_bt<EDP,256,false><<<dim3(MP_EDGE/128,2),256,0,stream>>>(e_bf, WtE, nullptr, Eemb, N_EDGES);
  edge_phase_kernel<<<MP_NODE/4,256,0,stream>>>(QKVS,Eemb,rowptr,csr,h_bf,nullptr,1);

  // ---- conv2 ----
  transpose_node_w<<<1024,256,0,stream>>>(Wq2,Wk2,Wv2,Ws2,WtN);
  bias_cat_kernel<<<4,256,0,stream>>>(bq2,bk2,bv2,bs2,biasN);
  transpose_edge_w<<<224,256,0,stream>>>(We2,WtE);
  gemm_bt<DIM,1024,true><<<dim3(MP_NODE/128,8),256,0,stream>>>(h_bf, WtN, biasN, QKVS, N_NODES);
  gemm_bt<EDP,256,false><<<dim3(MP_EDGE/128,2),256,0,stream>>>(e_bf, WtE, nullptr, Eemb, N_EDGES);
  edge_phase_kernel<<<N_NODES/4,256,0,stream>>>(QKVS,Eemb,rowptr,csr,nullptr,(float*)d_out,0);
}